// Round 1
// baseline (371.340 us; speedup 1.0000x reference)
//
#include <hip/hip_runtime.h>

// IntensityTransformation: out_k[b,c,h,w] = tf_k[b,c, round(255*img[b,c,h,w])]
// B=8, C=3, H=W=1024, LUT=256. Memory-bound LUT gather.
//
// v2: grid-stride batching. 64 blocks per plane (1536 total, ~6/CU, no tail),
// each thread handles 16 float4 (64 pixels) with 4 independent loads in
// flight per unrolled group. LUT staging (3 KB LDS) amortized 16x vs v1.

#define PLANES 24                                   // B*C
#define PLANE_PIX (1024 * 1024)
#define VEC4_PER_PLANE (PLANE_PIX / 4)              // 262144
#define BLOCK 256
#define CHUNKS 64                                   // blocks per plane
#define ITERS (VEC4_PER_PLANE / (CHUNKS * BLOCK))   // 16 float4 per thread
#define TOTAL_VEC4 (PLANES * VEC4_PER_PLANE)        // 6291456

// Gather+store for one float4 of pixels at element index (idx).
// Macro (not a function) so the LDS arrays keep their __shared__ addrspace
// and the compiler emits ds_read_b32, not flat loads.
#define DO_PIX4(v, idx)                                                 \
    do {                                                                \
        int i0 = __float2int_rn(255.0f * (v).x);                        \
        int i1 = __float2int_rn(255.0f * (v).y);                        \
        int i2 = __float2int_rn(255.0f * (v).z);                        \
        int i3 = __float2int_rn(255.0f * (v).w);                        \
        i0 = min(max(i0, 0), 255);                                      \
        i1 = min(max(i1, 0), 255);                                      \
        i2 = min(max(i2, 0), 255);                                      \
        i3 = min(max(i3, 0), 255);                                      \
        out[(idx)] = make_float4(l1[i0], l1[i1], l1[i2], l1[i3]);       \
        out[(idx) + TOTAL_VEC4] =                                       \
            make_float4(l2[i0], l2[i1], l2[i2], l2[i3]);                \
        out[(idx) + 2 * TOTAL_VEC4] =                                   \
            make_float4(l3[i0], l3[i1], l3[i2], l3[i3]);                \
    } while (0)

__global__ __launch_bounds__(BLOCK) void intensity_lut_kernel(
    const float4* __restrict__ img,
    const float*  __restrict__ tf1,
    const float*  __restrict__ tf2,
    const float*  __restrict__ tf3,
    float4* __restrict__ out)
{
    __shared__ float l1[256];
    __shared__ float l2[256];
    __shared__ float l3[256];

    const int plane = blockIdx.y;      // 0..23
    const int t = threadIdx.x;         // 0..255

    // Stage this plane's LUTs into LDS once per block (amortized over ITERS).
    l1[t] = tf1[plane * 256 + t];
    l2[t] = tf2[plane * 256 + t];
    l3[t] = tf3[plane * 256 + t];
    __syncthreads();

    // Element indices fit in int32: max = 3*TOTAL_VEC4 = 18.9M.
    const int base = plane * VEC4_PER_PLANE
                   + blockIdx.x * (BLOCK * ITERS) + t;

    #pragma unroll
    for (int k = 0; k < ITERS; k += 4) {
        // 4 independent loads in flight (MLP), then dependent gathers.
        float4 v0 = img[base + (k + 0) * BLOCK];
        float4 v1 = img[base + (k + 1) * BLOCK];
        float4 v2 = img[base + (k + 2) * BLOCK];
        float4 v3 = img[base + (k + 3) * BLOCK];

        DO_PIX4(v0, base + (k + 0) * BLOCK);
        DO_PIX4(v1, base + (k + 1) * BLOCK);
        DO_PIX4(v2, base + (k + 2) * BLOCK);
        DO_PIX4(v3, base + (k + 3) * BLOCK);
    }
}

extern "C" void kernel_launch(void* const* d_in, const int* in_sizes, int n_in,
                              void* d_out, int out_size, void* d_ws, size_t ws_size,
                              hipStream_t stream) {
    const float4* img = (const float4*)d_in[0];
    const float*  tf1 = (const float*)d_in[1];
    const float*  tf2 = (const float*)d_in[2];
    const float*  tf3 = (const float*)d_in[3];
    float4* out = (float4*)d_out;

    dim3 grid(CHUNKS, PLANES);
    dim3 block(BLOCK);
    intensity_lut_kernel<<<grid, block, 0, stream>>>(img, tf1, tf2, tf3, out);
}